// Round 11
// baseline (8244.086 us; speedup 1.0000x reference)
//
#include <hip/hip_runtime.h>
#include <math.h>

#define NB 512      // batch
#define NT 512      // time
#define NCTRL 256
#define NWORD 128
#define NMEM 128
#define NDIN 64
#define NACT 448    // x(64) | read(128) | ctrl(256)
#define EPSF 1e-6f
#define MPAD 130    // fp16 M row stride: 260 B = 65 words -> odd word stride
                    // => column access conflict-free, row h2 access 2-way (free)

// fp16 weight panel, CHUNK-TRANSPOSED layout (identical to prior rounds):
//   element(region, kc, col, e) at region_base + (kc*NCOLS + col)*8 + e
#define H_WA   0        // rz:    56 kc x 512 cols x 8
#define H_WNI  229376   // inn:   24 kc x 256 cols x 8
#define H_WNH  278528   // hn:    32 kc x 256 cols x 8
#define H_WH   344064   // heads: 32 kc x 512 cols x 8 (key|erase|add|beta|pad)
#define H_TOTAL 475136
#define B_BA   0        // [512] b_ih+b_hh (r,z)
#define B_BNI  512      // [256]
#define B_BNH  768      // [256]
#define B_BH   1024     // [512]
#define B_TOTAL 1536
#define WS_BYTES (H_TOTAL * 2 + B_TOTAL * 4)

typedef _Float16 h2 __attribute__((ext_vector_type(2)));
typedef _Float16 h8 __attribute__((ext_vector_type(8)));
union H8 { h8 v; h2 d[4]; };

__device__ __forceinline__ float sigf(float x) { return 1.0f / (1.0f + expf(-x)); }
__device__ __forceinline__ float softplusf(float x) {
    return (x > 15.0f) ? x : log1pf(expf(x));
}
__device__ __forceinline__ float fdot2(h2 a, h2 b, float c) {
#if __has_builtin(__builtin_amdgcn_fdot2)
    return __builtin_amdgcn_fdot2(a, b, c, false);
#else
    return fmaf((float)a[0], (float)b[0], fmaf((float)a[1], (float)b[1], c));
#endif
}

// lgkm-only barrier (verified rounds 8/9/10): orders LDS without draining vmcnt.
__device__ __forceinline__ void barL() {
    asm volatile("s_waitcnt lgkmcnt(0)\n\ts_barrier" ::: "memory");
}

__global__ __launch_bounds__(256) void prep_kernel(
    const float* __restrict__ Wih, const float* __restrict__ bih,
    const float* __restrict__ Whh, const float* __restrict__ bhh,
    const float* __restrict__ Wkey, const float* __restrict__ bkey,
    const float* __restrict__ Wbeta, const float* __restrict__ bbeta,
    const float* __restrict__ Wer, const float* __restrict__ ber,
    const float* __restrict__ Wadd, const float* __restrict__ badd,
    _Float16* __restrict__ wsH, float* __restrict__ wsB)
{
    int i = blockIdx.x * 256 + threadIdx.x;
    if (i < H_TOTAL) {
        float v;
        if (i < H_WNI) {                       // rz [kc][512][8]
            int ch = i >> 3, e = i & 7;
            int kc = ch >> 9, col = ch & 511;
            int k = kc * 8 + e;
            v = (k < 192) ? Wih[col * 192 + k] : Whh[col * 256 + (k - 192)];
        } else if (i < H_WNH) {                // inn [kc][256][8], k<192
            int i2 = i - H_WNI; int ch = i2 >> 3, e = i2 & 7;
            int kc = ch >> 8, col = ch & 255;
            v = Wih[(512 + col) * 192 + kc * 8 + e];
        } else if (i < H_WH) {                 // hn [kc][256][8], k<256
            int i2 = i - H_WNH; int ch = i2 >> 3, e = i2 & 7;
            int kc = ch >> 8, col = ch & 255;
            v = Whh[(512 + col) * 256 + kc * 8 + e];
        } else {                               // heads [kc][512][8], k<256
            int i2 = i - H_WH; int ch = i2 >> 3, e = i2 & 7;
            int kc = ch >> 9, col = ch & 511;
            int k = kc * 8 + e;
            if (col < 128)       v = Wkey[col * 256 + k];
            else if (col < 256)  v = Wer[(col - 128) * 256 + k];
            else if (col < 384)  v = Wadd[(col - 256) * 256 + k];
            else if (col == 384) v = Wbeta[k];
            else                 v = 0.0f;
        }
        wsH[i] = (_Float16)v;
    } else if (i < H_TOTAL + B_TOTAL) {
        int j = i - H_TOTAL;
        float v;
        if (j < 512)        v = bih[j] + bhh[j];
        else if (j < 768)   v = bih[512 + (j - 512)];
        else if (j < 1024)  v = bhh[512 + (j - 768)];
        else {
            int c = j - 1024;
            if (c < 128)       v = bkey[c];
            else if (c < 256)  v = ber[c - 128];
            else if (c < 384)  v = badd[c - 256];
            else if (c == 384) v = bbeta[0];
            else               v = 0.0f;
        }
        wsB[j] = v;
    }
}

// Verified memory module (used by slow path only; fp32 M).
__device__ __forceinline__ void memory_step(
    int u, bool wr, float (*M)[NWORD + 1],
    const float* keyv, const float* ev, const float* av,
    float* cosb, float* wb, float* part, float* readv, float* scal)
{
    if (u < 64) {                       // ||k||
        float s = keyv[u] * keyv[u] + keyv[u + 64] * keyv[u + 64];
        #pragma unroll
        for (int o = 32; o >= 1; o >>= 1) s += __shfl_xor(s, o);
        if (u == 0) scal[0] = 1.0f / (sqrtf(s) + EPSF);
    }
    __syncthreads();
    {                                      // cosine sim: 2 threads / row
        int rr = u >> 1, hh = u & 1;
        const float* Mr = &M[rr][hh * 64];
        const float4* kk4 = (const float4*)(keyv + hh * 64);
        float s2 = 0.f, sc = 0.f;
        #pragma unroll
        for (int p = 0; p < 16; ++p) {
            float4 k4 = kk4[p];
            float m0 = Mr[4 * p], m1 = Mr[4 * p + 1], m2 = Mr[4 * p + 2], m3 = Mr[4 * p + 3];
            s2 = fmaf(m0, m0, s2); sc = fmaf(m0, k4.x, sc);
            s2 = fmaf(m1, m1, s2); sc = fmaf(m1, k4.y, sc);
            s2 = fmaf(m2, m2, s2); sc = fmaf(m2, k4.z, sc);
            s2 = fmaf(m3, m3, s2); sc = fmaf(m3, k4.w, sc);
        }
        s2 += __shfl_xor(s2, 1);
        sc += __shfl_xor(sc, 1);
        if (hh == 0) cosb[rr] = sc * scal[0] / (sqrtf(s2) + EPSF);
    }
    __syncthreads();
    if (u < 64) {                       // softmax over 128 logits
        float beta = scal[1];
        float l0 = beta * cosb[u], l1 = beta * cosb[u + 64];
        float mx = fmaxf(l0, l1);
        #pragma unroll
        for (int o = 32; o >= 1; o >>= 1) mx = fmaxf(mx, __shfl_xor(mx, o));
        float e0 = expf(l0 - mx), e1 = expf(l1 - mx);
        float s = e0 + e1;
        #pragma unroll
        for (int o = 32; o >= 1; o >>= 1) s += __shfl_xor(s, o);
        float inv = 1.0f / s;
        wb[u] = e0 * inv;
        wb[u + 64] = e1 * inv;
    }
    __syncthreads();
    {   // FUSED read+update
        int j = u & 127, rh = u >> 7;
        float ej = ev[j], aj = av[j];
        const float4* wb4 = (const float4*)(wb + rh * 64);
        float p = 0.f;
        #pragma unroll
        for (int pq = 0; pq < 16; ++pq) {
            float4 w4 = wb4[pq];
            int r = rh * 64 + 4 * pq;
            float m0 = M[r][j], m1 = M[r + 1][j], m2 = M[r + 2][j], m3 = M[r + 3][j];
            p = fmaf(w4.x, m0, p);
            p = fmaf(w4.y, m1, p);
            p = fmaf(w4.z, m2, p);
            p = fmaf(w4.w, m3, p);
            if (wr) {
                M[r][j]     = fmaf(-w4.x, fmaf(ej, m0, -aj), m0);
                M[r + 1][j] = fmaf(-w4.y, fmaf(ej, m1, -aj), m1);
                M[r + 2][j] = fmaf(-w4.z, fmaf(ej, m2, -aj), m2);
                M[r + 3][j] = fmaf(-w4.w, fmaf(ej, m3, -aj), m3);
            }
        }
        part[rh * 128 + j] = p;
    }
    __syncthreads();
    if (wr && u < 128) readv[u] = part[u] + part[128 + u];
}

#define DOT_RZ(WSRC) do { H8 w_; w_.v = (WSRC); \
    a0 = fdot2(x0.d[0], w_.d[0], a0); c0 = fdot2(x0.d[1], w_.d[1], c0); \
    a0 = fdot2(x0.d[2], w_.d[2], a0); c0 = fdot2(x0.d[3], w_.d[3], c0); \
    a1 = fdot2(x1.d[0], w_.d[0], a1); c1 = fdot2(x1.d[1], w_.d[1], c1); \
    a1 = fdot2(x1.d[2], w_.d[2], a1); c1 = fdot2(x1.d[3], w_.d[3], c1); } while (0)

#define DOT_AUX(WSRC) do { H8 w_; w_.v = (WSRC); \
    e0 = fdot2(x0.d[0], w_.d[0], e0); f0 = fdot2(x0.d[1], w_.d[1], f0); \
    e0 = fdot2(x0.d[2], w_.d[2], e0); f0 = fdot2(x0.d[3], w_.d[3], f0); \
    e1 = fdot2(x1.d[0], w_.d[0], e1); f1 = fdot2(x1.d[1], w_.d[1], f1); \
    e1 = fdot2(x1.d[2], w_.d[2], e1); f1 = fdot2(x1.d[3], w_.d[3], f1); } while (0)

#define DOT_HD(WSRC) do { H8 w_; w_.v = (WSRC); \
    h0 = fdot2(x0.d[0], w_.d[0], h0); d0 = fdot2(x0.d[1], w_.d[1], d0); \
    h0 = fdot2(x0.d[2], w_.d[2], h0); d0 = fdot2(x0.d[3], w_.d[3], d0); \
    h1 = fdot2(x1.d[0], w_.d[0], h1); d1 = fdot2(x1.d[1], w_.d[1], d1); \
    h1 = fdot2(x1.d[2], w_.d[2], h1); d1 = fdot2(x1.d[3], w_.d[3], d1); } while (0)

#define LOADX(KC) H8 x0; x0.v = A0[KC]; H8 x1; x1.v = A1[KC]

// Round-9 champion skeleton (512 thr, 2 rows/block, long unroll-4 sweeps,
// barL, kn2-fold, x-prefetch) with LDS squeezed under 80 KB so TWO blocks
// co-reside per CU (16 waves). Cross-WG overlap: while one WG runs its
// LDS-bound memory phases, the other streams weights -> L2 port stays busy
// (round-1 evidence: 2 WGs/CU sustained 48.6 B/cy; 1 WG only ~30).
// Changes vs round 9: M stored fp16 [130]-padded (compute fp32), phase-
// overlaid union buffer (gA/iA/hA <-> cosb/wb/part), readv master in a
// register. LDS total 81,704 B <= 81,920 (160K/2).
__global__ __launch_bounds__(512, 4) void ntm_fast9(
    const float* __restrict__ data, const int* __restrict__ batch_sizes,
    const int* __restrict__ unsort, const float* __restrict__ M0,
    const _Float16* __restrict__ wsH, const float* __restrict__ wsB,
    float* __restrict__ out)
{
    __shared__ _Float16 Mh[2][NMEM][MPAD];                // 66560 B
    __shared__ __align__(16) _Float16 actH[2][NACT];      // 1792 B
    __shared__ float ctrlB[2][NCTRL];                     // 2048 B
    __shared__ __align__(16) float ubuf[2048];            // 8192 B (overlaid)
    __shared__ __align__(16) float keyv[2][NWORD], ev[2][NWORD], av[2][NWORD];
    __shared__ float kn2[2][2], betav[2];
    __shared__ int len_sh[2], gpos[2];

    // sweep->gates overlay
    float (*gA)[512] = (float (*)[512])(ubuf);            // [2][512]
    float (*iA)[256] = (float (*)[256])(ubuf + 1024);     // [2][256]
    float (*hA)[256] = (float (*)[256])(ubuf + 1536);     // [2][256]
    // memory-phase overlay (aliases gA region; liveness disjoint)
    float (*cosb)[128] = (float (*)[128])(ubuf);          // [2][128]
    float (*wb)[128]   = (float (*)[128])(ubuf + 256);    // [2][128]
    float (*part)[256] = (float (*)[256])(ubuf + 512);    // [2][256]

    const int t = threadIdx.x;
    const int q = t >> 8;          // row half (0/1)
    const int u = t & 255;         // local tid within half
    const int g = blockIdx.x;
    const int b = 2 * g + q;       // this half's packed row

    if (t < 2) {
        int bb = 2 * g + t;
        int L = 0;
        for (int s = 0; s < NT; ++s) L += (batch_sizes[s] > bb);
        len_sh[t] = L;
    }
    {   // inverse permutation: find out-position of each packed row
        int ug = unsort[t];                 // t in [0,512) == NB
        if (ug == 2 * g)     gpos[0] = t;
        if (ug == 2 * g + 1) gpos[1] = t;
    }
    for (int i = t; i < 2 * NMEM * NWORD; i += 512) {
        int ii = i & (NMEM * NWORD - 1);
        Mh[i >> 14][ii >> 7][ii & 127] = (_Float16)M0[ii];
    }
    ctrlB[q][u] = 0.0f;
    actH[q][192 + u] = (_Float16)0.0f;
    __syncthreads();
    const int len0 = len_sh[0], len1 = len_sh[1];   // len0 >= len1 (packed order)

    const float bRZ  = wsB[B_BA + t];
    const float bAux = (t < 256) ? wsB[B_BNI + u] : wsB[B_BNH + u];
    const float bHD  = wsB[B_BH + t];

    const h8* __restrict__ pA  = (const h8*)(wsH + H_WA);
    const h8* __restrict__ pI  = (const h8*)(wsH + H_WNI);
    const h8* __restrict__ pH  = (const h8*)(wsH + H_WNH);
    const h8* __restrict__ pHD = (const h8*)(wsH + H_WH);
    const h8* A0 = (const h8*)actH[0];
    const h8* A1 = (const h8*)actH[1];

    float rv = 0.0f;                 // readv master (threads u<128 of each half)
    float xf = 0.0f;
    if (u >= 128 && u < 192) xf = data[((long)0 * NB + b) * NDIN + (u - 128)];

    for (int ts = 0; ts < len0; ++ts) {
        const bool wr = (q == 0) | (ts < len1);
        // ---- stage activations as fp16 (state masters stay fp32/regs)
        if (u < 128)      actH[q][64 + u] = (_Float16)rv;
        else if (u < 192) actH[q][u - 128] = (_Float16)xf;
        barL();

        // ---- fused sweep: rz col t (both rows) + aux col u  [round-2 loops]
        float a0 = bRZ, c0 = 0.f, a1 = bRZ, c1 = 0.f;
        float e0 = bAux, f0 = 0.f, e1 = bAux, f1 = 0.f;
        if (t < 256) {
            #pragma unroll 4
            for (int kc = 0; kc < 24; ++kc) {            // k in [0,192): rz + inn
                LOADX(kc);
                DOT_RZ(pA[kc * 512 + t]);
                DOT_AUX(pI[kc * 256 + u]);
            }
            #pragma unroll 4
            for (int kc = 24; kc < 56; ++kc) {           // k in [192,448): rz only
                LOADX(kc);
                DOT_RZ(pA[kc * 512 + t]);
            }
        } else {
            #pragma unroll 4
            for (int kc = 0; kc < 24; ++kc) {            // rz only
                LOADX(kc);
                DOT_RZ(pA[kc * 512 + t]);
            }
            #pragma unroll 4
            for (int kc = 24; kc < 56; ++kc) {           // rz + hn
                LOADX(kc);
                DOT_RZ(pA[kc * 512 + t]);
                DOT_AUX(pH[(kc - 24) * 256 + u]);
            }
        }
        gA[0][t] = a0 + c0;
        gA[1][t] = a1 + c1;
        if (t < 256) { iA[0][u] = e0 + f0; iA[1][u] = e1 + f1; }
        else         { hA[0][u] = e0 + f0; hA[1][u] = e1 + f1; }
        barL();

        {   // gate combine: thread (q,u) owns ctrl element u of row q
            float rg = sigf(gA[q][u]);
            float zg = sigf(gA[q][NCTRL + u]);
            float ng = tanhf(fmaf(rg, hA[q][u], iA[q][u]));
            float cold = ctrlB[q][u];
            float cnew = fmaf(zg, cold - ng, ng);
            if (wr) {
                ctrlB[q][u] = cnew;
                actH[q][192 + u] = (_Float16)cnew;
            }
        }
        barL();

        // ---- heads: col t for both rows + kn2 fold + x(ts+1) prefetch
        {
            float h0 = bHD, d0 = 0.f, h1 = bHD, d1 = 0.f;
            #pragma unroll 4
            for (int kc = 0; kc < 32; ++kc) {
                LOADX(24 + kc);
                DOT_HD(pHD[kc * 512 + t]);
            }
            h0 += d0; h1 += d1;
            if (t < 128) {
                float k0 = tanhf(h0), k1 = tanhf(h1);
                keyv[0][t] = k0; keyv[1][t] = k1;
                float s0 = k0 * k0, s1 = k1 * k1;
                #pragma unroll
                for (int o = 32; o >= 1; o >>= 1) {
                    s0 += __shfl_xor(s0, o);
                    s1 += __shfl_xor(s1, o);
                }
                if ((t & 63) == 0) { kn2[0][t >> 6] = s0; kn2[1][t >> 6] = s1; }
            }
            else if (t < 256)  { ev[0][t - 128] = sigf(h0); ev[1][t - 128] = sigf(h1); }
            else if (t < 384)  { av[0][t - 256] = h0;       av[1][t - 256] = h1; }
            else if (t == 384) { betav[0] = softplusf(h0);  betav[1] = softplusf(h1); }
            int tn = (ts + 1 < NT) ? (ts + 1) : (NT - 1);
            if (u >= 128 && u < 192) xf = data[((long)tn * NB + b) * NDIN + (u - 128)];
        }
        barL();

        // ---- cosine sim (2 threads / mem-row); fp16 M, fp32 math
        {
            float invk = 1.0f / (sqrtf(kn2[q][0] + kn2[q][1]) + EPSF);
            int rr = u >> 1, hh = u & 1;
            const h2* Mr2 = (const h2*)&Mh[q][rr][hh * 64];
            const float4* kk4 = (const float4*)(&keyv[q][hh * 64]);
            float s2 = 0.f, sc = 0.f;
            #pragma unroll
            for (int p = 0; p < 16; ++p) {
                float4 k4 = kk4[p];
                h2 ma = Mr2[2 * p], mb = Mr2[2 * p + 1];
                float m0 = (float)ma[0], m1 = (float)ma[1];
                float m2v = (float)mb[0], m3 = (float)mb[1];
                s2 = fmaf(m0, m0, s2);   sc = fmaf(m0, k4.x, sc);
                s2 = fmaf(m1, m1, s2);   sc = fmaf(m1, k4.y, sc);
                s2 = fmaf(m2v, m2v, s2); sc = fmaf(m2v, k4.z, sc);
                s2 = fmaf(m3, m3, s2);   sc = fmaf(m3, k4.w, sc);
            }
            s2 += __shfl_xor(s2, 1);
            sc += __shfl_xor(sc, 1);
            if (hh == 0) cosb[q][rr] = sc * invk / (sqrtf(s2) + EPSF);
        }
        barL();

        // ---- softmax over 128 logits (64 threads per half)
        if (u < 64) {
            float beta = betav[q];
            float l0 = beta * cosb[q][u], l1 = beta * cosb[q][u + 64];
            float mx = fmaxf(l0, l1);
            #pragma unroll
            for (int o = 32; o >= 1; o >>= 1) mx = fmaxf(mx, __shfl_xor(mx, o));
            float se0 = expf(l0 - mx), se1 = expf(l1 - mx);
            float s = se0 + se1;
            #pragma unroll
            for (int o = 32; o >= 1; o >>= 1) s += __shfl_xor(s, o);
            float inv = 1.0f / s;
            wb[q][u] = se0 * inv;
            wb[q][u + 64] = se1 * inv;
        }
        barL();

        // ---- FUSED read+update (fp16 M, fp32 math)
        {
            int j = u & 127, rh = u >> 7;
            float ej = ev[q][j], aj = av[q][j];
            const float4* wb4 = (const float4*)(&wb[q][rh * 64]);
            float p = 0.f;
            #pragma unroll
            for (int pq = 0; pq < 16; ++pq) {
                float4 w4 = wb4[pq];
                int r = rh * 64 + 4 * pq;
                float m0 = (float)Mh[q][r][j],     m1 = (float)Mh[q][r + 1][j];
                float m2v = (float)Mh[q][r + 2][j], m3 = (float)Mh[q][r + 3][j];
                p = fmaf(w4.x, m0, p);
                p = fmaf(w4.y, m1, p);
                p = fmaf(w4.z, m2v, p);
                p = fmaf(w4.w, m3, p);
                if (wr) {
                    Mh[q][r][j]     = (_Float16)fmaf(-w4.x, fmaf(ej, m0, -aj), m0);
                    Mh[q][r + 1][j] = (_Float16)fmaf(-w4.y, fmaf(ej, m1, -aj), m1);
                    Mh[q][r + 2][j] = (_Float16)fmaf(-w4.z, fmaf(ej, m2v, -aj), m2v);
                    Mh[q][r + 3][j] = (_Float16)fmaf(-w4.w, fmaf(ej, m3, -aj), m3);
                }
            }
            part[q][rh * 128 + j] = p;
        }
        barL();
        if (wr && u < 128) rv = part[q][u] + part[q][128 + u];
        // rv produced and consumed by thread u -> no barrier here
    }

    out[gpos[q] * NCTRL + u] = ctrlB[q][u];
    if (u < NWORD) out[NB * NCTRL + gpos[q] * NWORD + u] = rv;
}

// FALLBACK (ws too small): verified slow path (fp32 M).
__global__ __launch_bounds__(256) void ntm_slow(
    const float* __restrict__ data, const int* __restrict__ batch_sizes,
    const int* __restrict__ unsort,
    const float* __restrict__ Wih, const float* __restrict__ bih,
    const float* __restrict__ Whh, const float* __restrict__ bhh,
    const float* __restrict__ Wkey, const float* __restrict__ bkey,
    const float* __restrict__ Wbeta, const float* __restrict__ bbeta,
    const float* __restrict__ Wer, const float* __restrict__ ber,
    const float* __restrict__ Wadd, const float* __restrict__ badd,
    const float* __restrict__ M0, float* __restrict__ out)
{
    __shared__ float M[NMEM][NWORD + 1];
    __shared__ float act[NACT];
    __shared__ float ctrlB[NCTRL];
    __shared__ float gpre[512], ginn[256], ghn[256], hpre[448];
    __shared__ __align__(16) float readv[NWORD], keyv[NWORD], ev[NWORD], av[NWORD];
    __shared__ __align__(16) float cosb[NMEM], wb[NMEM], part[2 * NWORD], scal[2];
    __shared__ int len_sh;

    const int tid = threadIdx.x;
    const int g = blockIdx.x;
    const int b = unsort[g];

    if (tid == 0) {
        int L = 0;
        for (int t = 0; t < NT; ++t) L += (batch_sizes[t] > b);
        len_sh = L;
    }
    for (int i = tid; i < NMEM * NWORD; i += 256)
        M[i >> 7][i & 127] = M0[i];
    ctrlB[tid] = 0.0f;
    if (tid < NWORD) readv[tid] = 0.0f;
    __syncthreads();
    const int len = len_sh;
    const int wave = tid >> 6, lane = tid & 63;

    for (int t = 0; t < len; ++t) {
        if (tid < 64)  act[tid] = data[((long)t * NB + b) * NDIN + tid];
        if (tid < 128) act[64 + tid] = readv[tid];
        act[192 + tid] = ctrlB[tid];
        __syncthreads();

        for (int j = wave; j < 512; j += 4) {
            float p = 0.f;
            for (int k = lane; k < 192; k += 64) p = fmaf(act[k], Wih[j * 192 + k], p);
            for (int k = lane; k < 256; k += 64) p = fmaf(act[192 + k], Whh[j * 256 + k], p);
            #pragma unroll
            for (int o = 32; o >= 1; o >>= 1) p += __shfl_xor(p, o);
            if (lane == 0) gpre[j] = p;
        }
        for (int j = wave; j < 256; j += 4) {
            float pi = 0.f, ph = 0.f;
            for (int k = lane; k < 192; k += 64) pi = fmaf(act[k], Wih[(512 + j) * 192 + k], pi);
            for (int k = lane; k < 256; k += 64) ph = fmaf(act[192 + k], Whh[(512 + j) * 256 + k], ph);
            #pragma unroll
            for (int o = 32; o >= 1; o >>= 1) { pi += __shfl_xor(pi, o); ph += __shfl_xor(ph, o); }
            if (lane == 0) { ginn[j] = pi; ghn[j] = ph; }
        }
        __syncthreads();
        {
            float r = sigf(gpre[tid] + bih[tid] + bhh[tid]);
            float z = sigf(gpre[256 + tid] + bih[256 + tid] + bhh[256 + tid]);
            float inn = ginn[tid] + bih[512 + tid];
            float hn  = ghn[tid] + bhh[512 + tid];
            float n = tanhf(fmaf(r, hn, inn));
            float cold = act[192 + tid];
            ctrlB[tid] = fmaf(z, cold - n, n);
        }
        __syncthreads();
        for (int j = wave; j < 385; j += 4) {
            const float* Wp; long base;
            if (j < 128)      { Wp = Wkey;  base = (long)j * 256; }
            else if (j < 256) { Wp = Wer;   base = (long)(j - 128) * 256; }
            else if (j < 384) { Wp = Wadd;  base = (long)(j - 256) * 256; }
            else              { Wp = Wbeta; base = 0; }
            float p = 0.f;
            for (int k = lane; k < 256; k += 64) p = fmaf(ctrlB[k], Wp[base + k], p);
            #pragma unroll
            for (int o = 32; o >= 1; o >>= 1) p += __shfl_xor(p, o);
            if (lane == 0) hpre[j] = p;
        }
        __syncthreads();
        if (tid < 128) {
            keyv[tid] = tanhf(hpre[tid] + bkey[tid]);
            ev[tid]   = sigf(hpre[128 + tid] + ber[tid]);
            av[tid]   = hpre[256 + tid] + badd[tid];
        }
        if (tid == 0) scal[1] = softplusf(hpre[384] + bbeta[0]);
        __syncthreads();

        memory_step(tid, true, M, keyv, ev, av, cosb, wb, part, readv, scal);
        __syncthreads();
    }

    out[g * NCTRL + tid] = ctrlB[tid];
    if (tid < NWORD) out[NB * NCTRL + g * NWORD + tid] = readv[tid];
}

extern "C" void kernel_launch(void* const* d_in, const int* in_sizes, int n_in,
                              void* d_out, int out_size, void* d_ws, size_t ws_size,
                              hipStream_t stream)
{
    const float* data       = (const float*)d_in[0];
    const int*  batch_sizes = (const int*)d_in[1];
    const int*  unsort      = (const int*)d_in[2];
    float* out = (float*)d_out;

    if (ws_size >= (size_t)WS_BYTES) {
        _Float16* wsH = (_Float16*)d_ws;
        float* wsB = (float*)((char*)d_ws + (size_t)H_TOTAL * 2);
        prep_kernel<<<(H_TOTAL + B_TOTAL + 255) / 256, 256, 0, stream>>>(
            (const float*)d_in[3], (const float*)d_in[4], (const float*)d_in[5],
            (const float*)d_in[6], (const float*)d_in[7], (const float*)d_in[8],
            (const float*)d_in[9], (const float*)d_in[10], (const float*)d_in[11],
            (const float*)d_in[12], (const float*)d_in[13], (const float*)d_in[14],
            wsH, wsB);
        ntm_fast9<<<NB / 2, 512, 0, stream>>>(data, batch_sizes, unsort,
                                              (const float*)d_in[15], wsH, wsB, out);
    } else {
        ntm_slow<<<NB, 256, 0, stream>>>(
            data, batch_sizes, unsort,
            (const float*)d_in[3], (const float*)d_in[4], (const float*)d_in[5],
            (const float*)d_in[6], (const float*)d_in[7], (const float*)d_in[8],
            (const float*)d_in[9], (const float*)d_in[10], (const float*)d_in[11],
            (const float*)d_in[12], (const float*)d_in[13], (const float*)d_in[14],
            (const float*)d_in[15], out);
    }
}

// Round 12
// 6575.161 us; speedup vs baseline: 1.2538x; 1.2538x over previous
//
#include <hip/hip_runtime.h>
#include <math.h>

#define NB 512      // batch
#define NT 512      // time
#define NCTRL 256
#define NWORD 128
#define NMEM 128
#define NDIN 64
#define NACT 448    // x(64) | read(128) | ctrl(256)
#define EPSF 1e-6f

// fp16 weight panel, CHUNK-TRANSPOSED layout (identical to prior rounds):
//   element(region, kc, col, e) at region_base + (kc*NCOLS + col)*8 + e
#define H_WA   0        // rz:    56 kc x 512 cols x 8
#define H_WNI  229376   // inn:   24 kc x 256 cols x 8
#define H_WNH  278528   // hn:    32 kc x 256 cols x 8
#define H_WH   344064   // heads: 32 kc x 512 cols x 8 (key|erase|add|beta|pad)
#define H_TOTAL 475136
#define B_BA   0        // [512] b_ih+b_hh (r,z)
#define B_BNI  512      // [256]
#define B_BNH  768      // [256]
#define B_BH   1024     // [512]
#define B_TOTAL 1536
#define WS_BYTES (H_TOTAL * 2 + B_TOTAL * 4)

typedef _Float16 h2 __attribute__((ext_vector_type(2)));
typedef _Float16 h8 __attribute__((ext_vector_type(8)));
union H8 { h8 v; h2 d[4]; };

__device__ __forceinline__ float sigf(float x) { return 1.0f / (1.0f + expf(-x)); }
__device__ __forceinline__ float softplusf(float x) {
    return (x > 15.0f) ? x : log1pf(expf(x));
}
__device__ __forceinline__ float fdot2(h2 a, h2 b, float c) {
#if __has_builtin(__builtin_amdgcn_fdot2)
    return __builtin_amdgcn_fdot2(a, b, c, false);
#else
    return fmaf((float)a[0], (float)b[0], fmaf((float)a[1], (float)b[1], c));
#endif
}

// lgkm-only barrier: orders LDS traffic without draining vmcnt (in-loop
// inter-thread communication is all via LDS; the compiler still inserts
// per-value vmcnt waits for each thread's own global loads).
// Verified correct in rounds 8/9 (passed, absmax identical).
__device__ __forceinline__ void barL() {
    asm volatile("s_waitcnt lgkmcnt(0)\n\ts_barrier" ::: "memory");
}

__global__ __launch_bounds__(256) void prep_kernel(
    const float* __restrict__ Wih, const float* __restrict__ bih,
    const float* __restrict__ Whh, const float* __restrict__ bhh,
    const float* __restrict__ Wkey, const float* __restrict__ bkey,
    const float* __restrict__ Wbeta, const float* __restrict__ bbeta,
    const float* __restrict__ Wer, const float* __restrict__ ber,
    const float* __restrict__ Wadd, const float* __restrict__ badd,
    _Float16* __restrict__ wsH, float* __restrict__ wsB)
{
    int i = blockIdx.x * 256 + threadIdx.x;
    if (i < H_TOTAL) {
        float v;
        if (i < H_WNI) {                       // rz [kc][512][8]
            int ch = i >> 3, e = i & 7;
            int kc = ch >> 9, col = ch & 511;
            int k = kc * 8 + e;
            v = (k < 192) ? Wih[col * 192 + k] : Whh[col * 256 + (k - 192)];
        } else if (i < H_WNH) {                // inn [kc][256][8], k<192
            int i2 = i - H_WNI; int ch = i2 >> 3, e = i2 & 7;
            int kc = ch >> 8, col = ch & 255;
            v = Wih[(512 + col) * 192 + kc * 8 + e];
        } else if (i < H_WH) {                 // hn [kc][256][8], k<256
            int i2 = i - H_WNH; int ch = i2 >> 3, e = i2 & 7;
            int kc = ch >> 8, col = ch & 255;
            v = Whh[(512 + col) * 256 + kc * 8 + e];
        } else {                               // heads [kc][512][8], k<256
            int i2 = i - H_WH; int ch = i2 >> 3, e = i2 & 7;
            int kc = ch >> 9, col = ch & 511;
            int k = kc * 8 + e;
            if (col < 128)       v = Wkey[col * 256 + k];
            else if (col < 256)  v = Wer[(col - 128) * 256 + k];
            else if (col < 384)  v = Wadd[(col - 256) * 256 + k];
            else if (col == 384) v = Wbeta[k];
            else                 v = 0.0f;
        }
        wsH[i] = (_Float16)v;
    } else if (i < H_TOTAL + B_TOTAL) {
        int j = i - H_TOTAL;
        float v;
        if (j < 512)        v = bih[j] + bhh[j];
        else if (j < 768)   v = bih[512 + (j - 512)];
        else if (j < 1024)  v = bhh[512 + (j - 768)];
        else {
            int c = j - 1024;
            if (c < 128)       v = bkey[c];
            else if (c < 256)  v = ber[c - 128];
            else if (c < 384)  v = badd[c - 256];
            else if (c == 384) v = bbeta[0];
            else               v = 0.0f;
        }
        wsB[j] = v;
    }
}

// Verified memory module (used by slow path only).
__device__ __forceinline__ void memory_step(
    int u, bool wr, float (*M)[NWORD + 1],
    const float* keyv, const float* ev, const float* av,
    float* cosb, float* wb, float* part, float* readv, float* scal)
{
    if (u < 64) {                       // ||k||
        float s = keyv[u] * keyv[u] + keyv[u + 64] * keyv[u + 64];
        #pragma unroll
        for (int o = 32; o >= 1; o >>= 1) s += __shfl_xor(s, o);
        if (u == 0) scal[0] = 1.0f / (sqrtf(s) + EPSF);
    }
    __syncthreads();
    {                                      // cosine sim: 2 threads / row
        int rr = u >> 1, hh = u & 1;
        const float* Mr = &M[rr][hh * 64];
        const float4* kk4 = (const float4*)(keyv + hh * 64);
        float s2 = 0.f, sc = 0.f;
        #pragma unroll
        for (int p = 0; p < 16; ++p) {
            float4 k4 = kk4[p];
            float m0 = Mr[4 * p], m1 = Mr[4 * p + 1], m2 = Mr[4 * p + 2], m3 = Mr[4 * p + 3];
            s2 = fmaf(m0, m0, s2); sc = fmaf(m0, k4.x, sc);
            s2 = fmaf(m1, m1, s2); sc = fmaf(m1, k4.y, sc);
            s2 = fmaf(m2, m2, s2); sc = fmaf(m2, k4.z, sc);
            s2 = fmaf(m3, m3, s2); sc = fmaf(m3, k4.w, sc);
        }
        s2 += __shfl_xor(s2, 1);
        sc += __shfl_xor(sc, 1);
        if (hh == 0) cosb[rr] = sc * scal[0] / (sqrtf(s2) + EPSF);
    }
    __syncthreads();
    if (u < 64) {                       // softmax over 128 logits
        float beta = scal[1];
        float l0 = beta * cosb[u], l1 = beta * cosb[u + 64];
        float mx = fmaxf(l0, l1);
        #pragma unroll
        for (int o = 32; o >= 1; o >>= 1) mx = fmaxf(mx, __shfl_xor(mx, o));
        float e0 = expf(l0 - mx), e1 = expf(l1 - mx);
        float s = e0 + e1;
        #pragma unroll
        for (int o = 32; o >= 1; o >>= 1) s += __shfl_xor(s, o);
        float inv = 1.0f / s;
        wb[u] = e0 * inv;
        wb[u + 64] = e1 * inv;
    }
    __syncthreads();
    {   // FUSED read+update
        int j = u & 127, rh = u >> 7;
        float ej = ev[j], aj = av[j];
        const float4* wb4 = (const float4*)(wb + rh * 64);
        float p = 0.f;
        #pragma unroll
        for (int pq = 0; pq < 16; ++pq) {
            float4 w4 = wb4[pq];
            int r = rh * 64 + 4 * pq;
            float m0 = M[r][j], m1 = M[r + 1][j], m2 = M[r + 2][j], m3 = M[r + 3][j];
            p = fmaf(w4.x, m0, p);
            p = fmaf(w4.y, m1, p);
            p = fmaf(w4.z, m2, p);
            p = fmaf(w4.w, m3, p);
            if (wr) {
                M[r][j]     = fmaf(-w4.x, fmaf(ej, m0, -aj), m0);
                M[r + 1][j] = fmaf(-w4.y, fmaf(ej, m1, -aj), m1);
                M[r + 2][j] = fmaf(-w4.z, fmaf(ej, m2, -aj), m2);
                M[r + 3][j] = fmaf(-w4.w, fmaf(ej, m3, -aj), m3);
            }
        }
        part[rh * 128 + j] = p;
    }
    __syncthreads();
    if (wr && u < 128) readv[u] = part[u] + part[128 + u];
}

#define DOT_RZ(WSRC) do { H8 w_; w_.v = (WSRC); \
    a0 = fdot2(x0.d[0], w_.d[0], a0); c0 = fdot2(x0.d[1], w_.d[1], c0); \
    a0 = fdot2(x0.d[2], w_.d[2], a0); c0 = fdot2(x0.d[3], w_.d[3], c0); \
    a1 = fdot2(x1.d[0], w_.d[0], a1); c1 = fdot2(x1.d[1], w_.d[1], c1); \
    a1 = fdot2(x1.d[2], w_.d[2], a1); c1 = fdot2(x1.d[3], w_.d[3], c1); } while (0)

#define DOT_AUX(WSRC) do { H8 w_; w_.v = (WSRC); \
    e0 = fdot2(x0.d[0], w_.d[0], e0); f0 = fdot2(x0.d[1], w_.d[1], f0); \
    e0 = fdot2(x0.d[2], w_.d[2], e0); f0 = fdot2(x0.d[3], w_.d[3], f0); \
    e1 = fdot2(x1.d[0], w_.d[0], e1); f1 = fdot2(x1.d[1], w_.d[1], f1); \
    e1 = fdot2(x1.d[2], w_.d[2], e1); f1 = fdot2(x1.d[3], w_.d[3], f1); } while (0)

#define DOT_HD(WSRC) do { H8 w_; w_.v = (WSRC); \
    h0 = fdot2(x0.d[0], w_.d[0], h0); d0 = fdot2(x0.d[1], w_.d[1], d0); \
    h0 = fdot2(x0.d[2], w_.d[2], h0); d0 = fdot2(x0.d[3], w_.d[3], d0); \
    h1 = fdot2(x1.d[0], w_.d[0], h1); d1 = fdot2(x1.d[1], w_.d[1], d1); \
    h1 = fdot2(x1.d[2], w_.d[2], h1); d1 = fdot2(x1.d[3], w_.d[3], d1); } while (0)

#define LOADX(KC) H8 x0; x0.v = A0[KC]; H8 x1; x1.v = A1[KC]

// SESSION CHAMPION (round 9, 6521 us): 512 thr, 2 rows/block (weights
// loaded from L2 once per block-step), long unroll-4 sweeps, barL lgkm-only
// barriers, ||k||^2 folded into heads phase, x(t+1) register prefetch.
// Verified counter profile: 96 VGPR (no spill), FETCH 28.9 MB, VALUBusy 38%,
// Occupancy 18.4% (1 WG/CU, LDS-capped).
// Levers tested and rejected with counter evidence:
//  - persistent/deep reg caching (r4/6/10): allocator pins <=128 regs -> spill
//  - 1024-thr / 2-WG-per-CU (r7/11): 64-reg pin + LDS co-residency denied
//  - sweep/memory software pipelining (r8): segmentation breaks load streaming
__global__ __launch_bounds__(512) void ntm_fast7(
    const float* __restrict__ data, const int* __restrict__ batch_sizes,
    const int* __restrict__ unsort, const float* __restrict__ M0,
    const _Float16* __restrict__ wsH, const float* __restrict__ wsB,
    float* __restrict__ out)
{
    __shared__ float M[2][NMEM][NWORD + 1];               // 132096 B
    __shared__ __align__(16) _Float16 actH[2][NACT];      // 1792 B
    __shared__ float ctrlB[2][NCTRL];
    __shared__ float gA[2][512];
    __shared__ float iA[2][NCTRL];
    __shared__ float hA[2][NCTRL];
    __shared__ __align__(16) float readv[2][NWORD], keyv[2][NWORD], ev[2][NWORD], av[2][NWORD];
    __shared__ __align__(16) float cosb[2][NMEM], wb[2][NMEM], part[2][2 * NWORD];
    __shared__ float kn2[2][2], betav[2];
    __shared__ int len_sh[2], gpos[2];

    const int t = threadIdx.x;
    const int q = t >> 8;          // row half (0/1)
    const int u = t & 255;         // local tid within half
    const int g = blockIdx.x;
    const int b = 2 * g + q;       // this half's packed row

    if (t < 2) {
        int bb = 2 * g + t;
        int L = 0;
        for (int s = 0; s < NT; ++s) L += (batch_sizes[s] > bb);
        len_sh[t] = L;
    }
    {   // inverse permutation: find out-position of each packed row
        int ug = unsort[t];                 // t in [0,512) == NB
        if (ug == 2 * g)     gpos[0] = t;
        if (ug == 2 * g + 1) gpos[1] = t;
    }
    for (int i = t; i < 2 * NMEM * NWORD; i += 512) {
        int ii = i & (NMEM * NWORD - 1);
        M[i >> 14][ii >> 7][ii & 127] = M0[ii];
    }
    ctrlB[q][u] = 0.0f;
    actH[q][192 + u] = (_Float16)0.0f;
    if (u < NWORD) readv[q][u] = 0.0f;
    __syncthreads();
    const int len0 = len_sh[0], len1 = len_sh[1];   // len0 >= len1 (packed order)

    const float bRZ  = wsB[B_BA + t];
    const float bAux = (t < 256) ? wsB[B_BNI + u] : wsB[B_BNH + u];
    const float bHD  = wsB[B_BH + t];

    const h8* __restrict__ pA  = (const h8*)(wsH + H_WA);
    const h8* __restrict__ pI  = (const h8*)(wsH + H_WNI);
    const h8* __restrict__ pH  = (const h8*)(wsH + H_WNH);
    const h8* __restrict__ pHD = (const h8*)(wsH + H_WH);
    const h8* A0 = (const h8*)actH[0];
    const h8* A1 = (const h8*)actH[1];

    float xf = 0.0f;
    if (u >= 128 && u < 192) xf = data[((long)0 * NB + b) * NDIN + (u - 128)];

    for (int ts = 0; ts < len0; ++ts) {
        const bool wr = (q == 0) | (ts < len1);
        // ---- stage activations as fp16 (state masters stay fp32)
        if (u < 128)      actH[q][64 + u] = (_Float16)readv[q][u];
        else if (u < 192) actH[q][u - 128] = (_Float16)xf;
        barL();

        // ---- fused sweep: rz col t (both rows) + aux col u  [round-2 loops]
        float a0 = bRZ, c0 = 0.f, a1 = bRZ, c1 = 0.f;
        float e0 = bAux, f0 = 0.f, e1 = bAux, f1 = 0.f;
        if (t < 256) {
            #pragma unroll 4
            for (int kc = 0; kc < 24; ++kc) {            // k in [0,192): rz + inn
                LOADX(kc);
                DOT_RZ(pA[kc * 512 + t]);
                DOT_AUX(pI[kc * 256 + u]);
            }
            #pragma unroll 4
            for (int kc = 24; kc < 56; ++kc) {           // k in [192,448): rz only
                LOADX(kc);
                DOT_RZ(pA[kc * 512 + t]);
            }
        } else {
            #pragma unroll 4
            for (int kc = 0; kc < 24; ++kc) {            // rz only
                LOADX(kc);
                DOT_RZ(pA[kc * 512 + t]);
            }
            #pragma unroll 4
            for (int kc = 24; kc < 56; ++kc) {           // rz + hn
                LOADX(kc);
                DOT_RZ(pA[kc * 512 + t]);
                DOT_AUX(pH[(kc - 24) * 256 + u]);
            }
        }
        gA[0][t] = a0 + c0;
        gA[1][t] = a1 + c1;
        if (t < 256) { iA[0][u] = e0 + f0; iA[1][u] = e1 + f1; }
        else         { hA[0][u] = e0 + f0; hA[1][u] = e1 + f1; }
        barL();

        {   // gate combine: thread (q,u) owns ctrl element u of row q
            float rg = sigf(gA[q][u]);
            float zg = sigf(gA[q][NCTRL + u]);
            float ng = tanhf(fmaf(rg, hA[q][u], iA[q][u]));
            float cold = ctrlB[q][u];
            float cnew = fmaf(zg, cold - ng, ng);
            if (wr) {
                ctrlB[q][u] = cnew;
                actH[q][192 + u] = (_Float16)cnew;
            }
        }
        barL();

        // ---- heads: col t for both rows + kn2 fold + x(ts+1) prefetch
        {
            float h0 = bHD, d0 = 0.f, h1 = bHD, d1 = 0.f;
            #pragma unroll 4
            for (int kc = 0; kc < 32; ++kc) {
                LOADX(24 + kc);
                DOT_HD(pHD[kc * 512 + t]);
            }
            h0 += d0; h1 += d1;
            if (t < 128) {
                float k0 = tanhf(h0), k1 = tanhf(h1);
                keyv[0][t] = k0; keyv[1][t] = k1;
                // fold ||k||^2: per-wave butterfly, 2 partials per row
                float s0 = k0 * k0, s1 = k1 * k1;
                #pragma unroll
                for (int o = 32; o >= 1; o >>= 1) {
                    s0 += __shfl_xor(s0, o);
                    s1 += __shfl_xor(s1, o);
                }
                if ((t & 63) == 0) { kn2[0][t >> 6] = s0; kn2[1][t >> 6] = s1; }
            }
            else if (t < 256)  { ev[0][t - 128] = sigf(h0); ev[1][t - 128] = sigf(h1); }
            else if (t < 384)  { av[0][t - 256] = h0;       av[1][t - 256] = h1; }
            else if (t == 384) { betav[0] = softplusf(h0);  betav[1] = softplusf(h1); }
            // prefetch next x; lands during the memory phases below
            int tn = (ts + 1 < NT) ? (ts + 1) : (NT - 1);
            if (u >= 128 && u < 192) xf = data[((long)tn * NB + b) * NDIN + (u - 128)];
        }
        barL();

        // ---- cosine sim (2 threads / mem-row); uses kn2 (no ||k|| phase)
        {
            float invk = 1.0f / (sqrtf(kn2[q][0] + kn2[q][1]) + EPSF);
            int rr = u >> 1, hh = u & 1;
            const float* Mr = &M[q][rr][hh * 64];
            const float4* kk4 = (const float4*)(&keyv[q][hh * 64]);
            float s2 = 0.f, sc = 0.f;
            #pragma unroll
            for (int p = 0; p < 16; ++p) {
                float4 k4 = kk4[p];
                float m0 = Mr[4 * p], m1 = Mr[4 * p + 1], m2 = Mr[4 * p + 2], m3 = Mr[4 * p + 3];
                s2 = fmaf(m0, m0, s2); sc = fmaf(m0, k4.x, sc);
                s2 = fmaf(m1, m1, s2); sc = fmaf(m1, k4.y, sc);
                s2 = fmaf(m2, m2, s2); sc = fmaf(m2, k4.z, sc);
                s2 = fmaf(m3, m3, s2); sc = fmaf(m3, k4.w, sc);
            }
            s2 += __shfl_xor(s2, 1);
            sc += __shfl_xor(sc, 1);
            if (hh == 0) cosb[q][rr] = sc * invk / (sqrtf(s2) + EPSF);
        }
        barL();

        // ---- softmax over 128 logits (64 threads per half)
        if (u < 64) {
            float beta = betav[q];
            float l0 = beta * cosb[q][u], l1 = beta * cosb[q][u + 64];
            float mx = fmaxf(l0, l1);
            #pragma unroll
            for (int o = 32; o >= 1; o >>= 1) mx = fmaxf(mx, __shfl_xor(mx, o));
            float se0 = expf(l0 - mx), se1 = expf(l1 - mx);
            float s = se0 + se1;
            #pragma unroll
            for (int o = 32; o >= 1; o >>= 1) s += __shfl_xor(s, o);
            float inv = 1.0f / s;
            wb[q][u] = se0 * inv;
            wb[q][u + 64] = se1 * inv;
        }
        barL();

        // ---- FUSED read+update
        {
            int j = u & 127, rh = u >> 7;
            float ej = ev[q][j], aj = av[q][j];
            const float4* wb4 = (const float4*)(&wb[q][rh * 64]);
            float p = 0.f;
            #pragma unroll
            for (int pq = 0; pq < 16; ++pq) {
                float4 w4 = wb4[pq];
                int r = rh * 64 + 4 * pq;
                float m0 = M[q][r][j], m1 = M[q][r + 1][j], m2 = M[q][r + 2][j], m3 = M[q][r + 3][j];
                p = fmaf(w4.x, m0, p);
                p = fmaf(w4.y, m1, p);
                p = fmaf(w4.z, m2, p);
                p = fmaf(w4.w, m3, p);
                if (wr) {
                    M[q][r][j]     = fmaf(-w4.x, fmaf(ej, m0, -aj), m0);
                    M[q][r + 1][j] = fmaf(-w4.y, fmaf(ej, m1, -aj), m1);
                    M[q][r + 2][j] = fmaf(-w4.z, fmaf(ej, m2, -aj), m2);
                    M[q][r + 3][j] = fmaf(-w4.w, fmaf(ej, m3, -aj), m3);
                }
            }
            part[q][rh * 128 + j] = p;
        }
        barL();
        if (wr && u < 128) readv[q][u] = part[q][u] + part[q][128 + u];
        // readv[u] produced and consumed by thread u -> no barrier here
    }

    out[gpos[q] * NCTRL + u] = ctrlB[q][u];
    if (u < NWORD) out[NB * NCTRL + gpos[q] * NWORD + u] = readv[q][u];
}

// FALLBACK (ws too small): verified slow path.
__global__ __launch_bounds__(256) void ntm_slow(
    const float* __restrict__ data, const int* __restrict__ batch_sizes,
    const int* __restrict__ unsort,
    const float* __restrict__ Wih, const float* __restrict__ bih,
    const float* __restrict__ Whh, const float* __restrict__ bhh,
    const float* __restrict__ Wkey, const float* __restrict__ bkey,
    const float* __restrict__ Wbeta, const float* __restrict__ bbeta,
    const float* __restrict__ Wer, const float* __restrict__ ber,
    const float* __restrict__ Wadd, const float* __restrict__ badd,
    const float* __restrict__ M0, float* __restrict__ out)
{
    __shared__ float M[NMEM][NWORD + 1];
    __shared__ float act[NACT];
    __shared__ float ctrlB[NCTRL];
    __shared__ float gpre[512], ginn[256], ghn[256], hpre[448];
    __shared__ __align__(16) float readv[NWORD], keyv[NWORD], ev[NWORD], av[NWORD];
    __shared__ __align__(16) float cosb[NMEM], wb[NMEM], part[2 * NWORD], scal[2];
    __shared__ int len_sh;

    const int tid = threadIdx.x;
    const int g = blockIdx.x;
    const int b = unsort[g];

    if (tid == 0) {
        int L = 0;
        for (int t = 0; t < NT; ++t) L += (batch_sizes[t] > b);
        len_sh = L;
    }
    for (int i = tid; i < NMEM * NWORD; i += 256)
        M[i >> 7][i & 127] = M0[i];
    ctrlB[tid] = 0.0f;
    if (tid < NWORD) readv[tid] = 0.0f;
    __syncthreads();
    const int len = len_sh;
    const int wave = tid >> 6, lane = tid & 63;

    for (int t = 0; t < len; ++t) {
        if (tid < 64)  act[tid] = data[((long)t * NB + b) * NDIN + tid];
        if (tid < 128) act[64 + tid] = readv[tid];
        act[192 + tid] = ctrlB[tid];
        __syncthreads();

        for (int j = wave; j < 512; j += 4) {
            float p = 0.f;
            for (int k = lane; k < 192; k += 64) p = fmaf(act[k], Wih[j * 192 + k], p);
            for (int k = lane; k < 256; k += 64) p = fmaf(act[192 + k], Whh[j * 256 + k], p);
            #pragma unroll
            for (int o = 32; o >= 1; o >>= 1) p += __shfl_xor(p, o);
            if (lane == 0) gpre[j] = p;
        }
        for (int j = wave; j < 256; j += 4) {
            float pi = 0.f, ph = 0.f;
            for (int k = lane; k < 192; k += 64) pi = fmaf(act[k], Wih[(512 + j) * 192 + k], pi);
            for (int k = lane; k < 256; k += 64) ph = fmaf(act[192 + k], Whh[(512 + j) * 256 + k], ph);
            #pragma unroll
            for (int o = 32; o >= 1; o >>= 1) { pi += __shfl_xor(pi, o); ph += __shfl_xor(ph, o); }
            if (lane == 0) { ginn[j] = pi; ghn[j] = ph; }
        }
        __syncthreads();
        {
            float r = sigf(gpre[tid] + bih[tid] + bhh[tid]);
            float z = sigf(gpre[256 + tid] + bih[256 + tid] + bhh[256 + tid]);
            float inn = ginn[tid] + bih[512 + tid];
            float hn  = ghn[tid] + bhh[512 + tid];
            float n = tanhf(fmaf(r, hn, inn));
            float cold = act[192 + tid];
            ctrlB[tid] = fmaf(z, cold - n, n);
        }
        __syncthreads();
        for (int j = wave; j < 385; j += 4) {
            const float* Wp; long base;
            if (j < 128)      { Wp = Wkey;  base = (long)j * 256; }
            else if (j < 256) { Wp = Wer;   base = (long)(j - 128) * 256; }
            else if (j < 384) { Wp = Wadd;  base = (long)(j - 256) * 256; }
            else              { Wp = Wbeta; base = 0; }
            float p = 0.f;
            for (int k = lane; k < 256; k += 64) p = fmaf(ctrlB[k], Wp[base + k], p);
            #pragma unroll
            for (int o = 32; o >= 1; o >>= 1) p += __shfl_xor(p, o);
            if (lane == 0) hpre[j] = p;
        }
        __syncthreads();
        if (tid < 128) {
            keyv[tid] = tanhf(hpre[tid] + bkey[tid]);
            ev[tid]   = sigf(hpre[128 + tid] + ber[tid]);
            av[tid]   = hpre[256 + tid] + badd[tid];
        }
        if (tid == 0) scal[1] = softplusf(hpre[384] + bbeta[0]);
        __syncthreads();

        memory_step(tid, true, M, keyv, ev, av, cosb, wb, part, readv, scal);
        __syncthreads();
    }

    out[g * NCTRL + tid] = ctrlB[tid];
    if (tid < NWORD) out[NB * NCTRL + g * NWORD + tid] = readv[tid];
}

extern "C" void kernel_launch(void* const* d_in, const int* in_sizes, int n_in,
                              void* d_out, int out_size, void* d_ws, size_t ws_size,
                              hipStream_t stream)
{
    const float* data       = (const float*)d_in[0];
    const int*  batch_sizes = (const int*)d_in[1];
    const int*  unsort      = (const int*)d_in[2];
    float* out = (float*)d_out;

    if (ws_size >= (size_t)WS_BYTES) {
        _Float16* wsH = (_Float16*)d_ws;
        float* wsB = (float*)((char*)d_ws + (size_t)H_TOTAL * 2);
        prep_kernel<<<(H_TOTAL + B_TOTAL + 255) / 256, 256, 0, stream>>>(
            (const float*)d_in[3], (const float*)d_in[4], (const float*)d_in[5],
            (const float*)d_in[6], (const float*)d_in[7], (const float*)d_in[8],
            (const float*)d_in[9], (const float*)d_in[10], (const float*)d_in[11],
            (const float*)d_in[12], (const float*)d_in[13], (const float*)d_in[14],
            wsH, wsB);
        ntm_fast7<<<NB / 2, 512, 0, stream>>>(data, batch_sizes, unsort,
                                              (const float*)d_in[15], wsH, wsB, out);
    } else {
        ntm_slow<<<NB, 256, 0, stream>>>(
            data, batch_sizes, unsort,
            (const float*)d_in[3], (const float*)d_in[4], (const float*)d_in[5],
            (const float*)d_in[6], (const float*)d_in[7], (const float*)d_in[8],
            (const float*)d_in[9], (const float*)d_in[10], (const float*)d_in[11],
            (const float*)d_in[12], (const float*)d_in[13], (const float*)d_in[14],
            (const float*)d_in[15], out);
    }
}